// Round 1
// baseline (161.596 us; speedup 1.0000x reference)
//
#include <hip/hip_runtime.h>
#include <hip/hip_bf16.h>

// ---------------------------------------------------------------------------
// SingleHead attention: q=xWq, k=xWk, v=xWv; causal softmax(qk^T/sqrt(64)) v
// B=8, T=2048, C=1024, D=64.  Output fp32 [B,T,64].
//
// Strategy:
//   k0: WT bf16 transpose of [Wq|Wk|Wv] (192x1024), 0.125 scale folded into q
//   k1: fused QKV projection GEMM (MFMA 16x16x32 bf16), W as A-operand,
//       x as B-operand; q,k row-major bf16, v stored transposed (vT[64][T])
//   k2: flash attention, 4 waves/block, 16 q-rows/wave, KV tile = 64
// ---------------------------------------------------------------------------

typedef __attribute__((ext_vector_type(8))) short short8;   // 8 x bf16 frag
typedef __attribute__((ext_vector_type(4))) float f32x4;    // C/D frag
typedef __attribute__((ext_vector_type(4))) unsigned int u32x4;

#define MFMA16(a, b, c) __builtin_amdgcn_mfma_f32_16x16x32_bf16((a), (b), (c), 0, 0, 0)

__device__ __forceinline__ unsigned short f2bf(float f) {
  unsigned int u = __builtin_bit_cast(unsigned int, f);
  unsigned int r = 0x7fffu + ((u >> 16) & 1u);
  return (unsigned short)((u + r) >> 16);
}

// --------------------------- constants -------------------------------------
#define BATCH 8
#define SEQ   2048
#define CDIM  1024
#define DDIM  64
#define NTOK  (BATCH * SEQ)   // 16384

// ---------------------------------------------------------------------------
// Kernel 0: WT[c'=0..191][k=0..1023] = W_{c' / 64}[k][c' % 64]  (bf16)
// q-columns (c' < 64) get the 1/sqrt(D) = 0.125 scale folded in.
// ---------------------------------------------------------------------------
__global__ __launch_bounds__(256) void wt_kernel(const float* __restrict__ Wq,
                                                 const float* __restrict__ Wk,
                                                 const float* __restrict__ Wv,
                                                 unsigned short* __restrict__ WT) {
  int tid = blockIdx.x * 256 + threadIdx.x;       // 0 .. 196607
  int c    = tid & 63;
  int rest = tid >> 6;
  int k    = rest & 1023;
  int wi   = rest >> 10;                          // 0,1,2
  const float* W = (wi == 0) ? Wq : ((wi == 1) ? Wk : Wv);
  float v = W[k * DDIM + c];                      // coalesced read
  if (wi == 0) v *= 0.125f;
  WT[(size_t)(wi * 64 + c) * CDIM + k] = f2bf(v);
}

// ---------------------------------------------------------------------------
// Kernel 1: fused QKV projection.
//   A = WT rows (feature dim, M=192), B = x tokens (N), K = 1024.
//   Block: 256 thr = 4 waves, 64 tokens/block; each wave: 16 tokens x 192 c.
//   LDS: WT slice [192][32] padded to [192][40] bf16.
// ---------------------------------------------------------------------------
__global__ __launch_bounds__(256) void proj_kernel(const float* __restrict__ x,
                                                   const unsigned short* __restrict__ WT,
                                                   unsigned short* __restrict__ qws,
                                                   unsigned short* __restrict__ kws,
                                                   unsigned short* __restrict__ vtws) {
  __shared__ unsigned short wl[192 * 40];

  const int n0   = blockIdx.x * 64;
  const int tid  = threadIdx.x;
  const int lane = tid & 63;
  const int w    = tid >> 6;
  const int c16  = lane & 15;      // token lane (B-operand col / D col)
  const int hi   = lane >> 4;      // k-group
  const int token = n0 + w * 16 + c16;

  f32x4 acc[12];
#pragma unroll
  for (int i = 0; i < 12; ++i) acc[i] = (f32x4){0.f, 0.f, 0.f, 0.f};

  const float* xrow = x + (size_t)token * CDIM;

  for (int k0 = 0; k0 < CDIM; k0 += 32) {
    __syncthreads();   // protect previous iteration's LDS reads
    {
      // stage WT[:, k0..k0+31]: 4 threads per c-row, 16B each, 3 passes
      int cc = tid >> 2;
      int kk = (tid & 3) * 8;
#pragma unroll
      for (int i = 0; i < 3; ++i) {
        int c = cc + i * 64;
        u32x4 v = *reinterpret_cast<const u32x4*>(WT + (size_t)c * CDIM + k0 + kk);
        *reinterpret_cast<u32x4*>(&wl[c * 40 + kk]) = v;
      }
    }
    __syncthreads();

    // B fragment: x[token][k0 + hi*8 .. +7], fp32 -> bf16
    float xf[8];
    *reinterpret_cast<f32x4*>(&xf[0]) = *reinterpret_cast<const f32x4*>(xrow + k0 + hi * 8);
    *reinterpret_cast<f32x4*>(&xf[4]) = *reinterpret_cast<const f32x4*>(xrow + k0 + hi * 8 + 4);
    short8 bx;
#pragma unroll
    for (int j = 0; j < 8; ++j) bx[j] = (short)f2bf(xf[j]);

#pragma unroll
    for (int ct = 0; ct < 12; ++ct) {
      short8 a = *reinterpret_cast<const short8*>(&wl[(ct * 16 + c16) * 40 + hi * 8]);
      acc[ct] = MFMA16(a, bx, acc[ct]);
    }
  }

  // Epilogue: lane holds D[c = ct*16 + hi*4 + r][token], r = 0..3
  const int b = token >> 11;
  const int t = token & 2047;
#pragma unroll
  for (int ct = 0; ct < 12; ++ct) {
    int cg = ct * 16 + hi * 4;
    unsigned short h[4];
#pragma unroll
    for (int r = 0; r < 4; ++r) h[r] = f2bf(acc[ct][r]);
    if (cg < 64) {
      ushort4 h4 = make_ushort4(h[0], h[1], h[2], h[3]);
      *reinterpret_cast<ushort4*>(qws + (size_t)token * DDIM + cg) = h4;
    } else if (cg < 128) {
      ushort4 h4 = make_ushort4(h[0], h[1], h[2], h[3]);
      *reinterpret_cast<ushort4*>(kws + (size_t)token * DDIM + (cg - 64)) = h4;
    } else {
      int cv = cg - 128;
#pragma unroll
      for (int r = 0; r < 4; ++r)
        vtws[(size_t)(b * DDIM + cv + r) * SEQ + t] = h[r];
    }
  }
}

// ---------------------------------------------------------------------------
// Kernel 2: causal flash attention.
//   Grid (T/64, B), 256 thr = 4 waves; wave w owns q-rows [bq*64+16w, +16).
//   KV tiles of 64; S-tile = 16x64 (4 C/D tiles, 8 MFMAs); PV via per-wave
//   LDS P buffer [16][72] bf16.
// ---------------------------------------------------------------------------
__global__ __launch_bounds__(256) void attn_kernel(const unsigned short* __restrict__ qws,
                                                   const unsigned short* __restrict__ kws,
                                                   const unsigned short* __restrict__ vtws,
                                                   float* __restrict__ out) {
  __shared__ unsigned short plds[4][16 * 72];

  const int bq   = blockIdx.x;
  const int b    = blockIdx.y;
  const int tid  = threadIdx.x;
  const int lane = tid & 63;
  const int w    = tid >> 6;
  const int c    = lane & 15;
  const int hi   = lane >> 4;
  const int qr0  = bq * 64 + w * 16;

  const unsigned short* qb = qws + (size_t)b * SEQ * DDIM;
  const unsigned short* kb = kws + (size_t)b * SEQ * DDIM;
  const unsigned short* vb = vtws + (size_t)b * DDIM * SEQ;

  // Q fragments (row = c, k contiguous 8 per hi-group), kept in registers
  short8 aq0 = *reinterpret_cast<const short8*>(qb + (size_t)(qr0 + c) * DDIM + hi * 8);
  short8 aq1 = *reinterpret_cast<const short8*>(qb + (size_t)(qr0 + c) * DDIM + 32 + hi * 8);

  float m[4], lsum[4];
  f32x4 o[4];
#pragma unroll
  for (int r = 0; r < 4; ++r) { m[r] = -INFINITY; lsum[r] = 0.f; }
#pragma unroll
  for (int dn = 0; dn < 4; ++dn) o[dn] = (f32x4){0.f, 0.f, 0.f, 0.f};

  unsigned short* pw = plds[w];

  const int kv_last = qr0 + 15;                 // largest legal kv index
  const int ntiles  = (kv_last + 64) >> 6;      // ceil((kv_last+1)/64)

  for (int it = 0; it < ntiles; ++it) {
    const int kv0 = it * 64;

    // ---- S = q k^T  (scale already folded into q) ----
    f32x4 s[4];
#pragma unroll
    for (int n = 0; n < 4; ++n) {
      int col0 = kv0 + n * 16;
      if (col0 > kv_last) {                     // wave-uniform: fully masked
        s[n] = (f32x4){-INFINITY, -INFINITY, -INFINITY, -INFINITY};
        continue;
      }
      const unsigned short* krow = kb + (size_t)(col0 + c) * DDIM;
      short8 bk0 = *reinterpret_cast<const short8*>(krow + hi * 8);
      short8 bk1 = *reinterpret_cast<const short8*>(krow + 32 + hi * 8);
      f32x4 z = (f32x4){0.f, 0.f, 0.f, 0.f};
      z = MFMA16(aq0, bk0, z);
      s[n] = MFMA16(aq1, bk1, z);
    }

    // ---- causal mask (only near the diagonal) ----
    if (kv0 + 63 > qr0) {
#pragma unroll
      for (int n = 0; n < 4; ++n) {
        int col = kv0 + n * 16 + c;
#pragma unroll
        for (int r = 0; r < 4; ++r) {
          int row = qr0 + hi * 4 + r;
          if (col > row) s[n][r] = -INFINITY;
        }
      }
    }

    // ---- online softmax update ----
    float p[4][4];
    float oscale[4];
#pragma unroll
    for (int r = 0; r < 4; ++r) {
      float mx = fmaxf(fmaxf(s[0][r], s[1][r]), fmaxf(s[2][r], s[3][r]));
#pragma unroll
      for (int off = 1; off < 16; off <<= 1) mx = fmaxf(mx, __shfl_xor(mx, off, 64));
      float nm = fmaxf(m[r], mx);
      float sc = __builtin_exp2f((m[r] - nm) * 1.44269504f);
      m[r] = nm;
      float ssum = 0.f;
#pragma unroll
      for (int n = 0; n < 4; ++n) {
        float pv = __builtin_exp2f((s[n][r] - nm) * 1.44269504f);
        p[n][r] = pv;
        ssum += pv;
      }
#pragma unroll
      for (int off = 1; off < 16; off <<= 1) ssum += __shfl_xor(ssum, off, 64);
      lsum[r] = lsum[r] * sc + ssum;
      oscale[r] = sc;
    }
#pragma unroll
    for (int dn = 0; dn < 4; ++dn)
#pragma unroll
      for (int r = 0; r < 4; ++r) o[dn][r] *= oscale[r];

    // ---- P -> LDS (bf16), per-wave buffer, row stride 72 ----
#pragma unroll
    for (int n = 0; n < 4; ++n)
#pragma unroll
      for (int r = 0; r < 4; ++r)
        pw[(hi * 4 + r) * 72 + n * 16 + c] = f2bf(p[n][r]);

    // ---- PV: o += P * V ----
#pragma unroll
    for (int f = 0; f < 2; ++f) {
      short8 pa = *reinterpret_cast<const short8*>(&pw[c * 72 + f * 32 + hi * 8]);
#pragma unroll
      for (int dn = 0; dn < 4; ++dn) {
        short8 bv = *reinterpret_cast<const short8*>(
            vb + (size_t)(dn * 16 + c) * SEQ + kv0 + f * 32 + hi * 8);
        o[dn] = MFMA16(pa, bv, o[dn]);
      }
    }
  }

  // ---- epilogue ----
  float inv[4];
#pragma unroll
  for (int r = 0; r < 4; ++r) inv[r] = 1.f / lsum[r];
  float* ob = out + ((size_t)b * SEQ + qr0) * DDIM;
#pragma unroll
  for (int dn = 0; dn < 4; ++dn)
#pragma unroll
    for (int r = 0; r < 4; ++r)
      ob[(hi * 4 + r) * DDIM + dn * 16 + c] = o[dn][r] * inv[r];
}

// ---------------------------------------------------------------------------
extern "C" void kernel_launch(void* const* d_in, const int* in_sizes, int n_in,
                              void* d_out, int out_size, void* d_ws, size_t ws_size,
                              hipStream_t stream) {
  const float* x  = (const float*)d_in[0];
  const float* Wq = (const float*)d_in[1];
  const float* Wk = (const float*)d_in[2];
  const float* Wv = (const float*)d_in[3];
  float* out = (float*)d_out;

  unsigned short* qws  = (unsigned short*)d_ws;            // 16384*64 bf16 (2MB)
  unsigned short* kws  = qws + (size_t)NTOK * DDIM;        // 2MB
  unsigned short* vtws = kws + (size_t)NTOK * DDIM;        // 2MB (transposed v)
  unsigned short* WT   = vtws + (size_t)NTOK * DDIM;       // 192*1024 bf16 (384KB)

  wt_kernel<<<768, 256, 0, stream>>>(Wq, Wk, Wv, WT);
  proj_kernel<<<NTOK / 64, 256, 0, stream>>>(x, WT, qws, kws, vtws);
  attn_kernel<<<dim3(SEQ / 64, BATCH), 256, 0, stream>>>(qws, kws, vtws, out);
}